// Round 1
// baseline (474.043 us; speedup 1.0000x reference)
//
#include <hip/hip_runtime.h>

#define NB 4
#define NC 64
#define NH 256
#define NW 256

// Vertical scans: blockIdx.y==0 -> down (out slot 2), ==1 -> up (out slot 0).
// Thread per (b,c,w) column; consecutive threads = consecutive w -> coalesced.
__global__ __launch_bounds__(256) void irnn_vertical(
    const float* __restrict__ x,
    const float* __restrict__ w_down, const float* __restrict__ b_down,
    const float* __restrict__ w_up,   const float* __restrict__ b_up,
    float* __restrict__ out)
{
    int tid = blockIdx.x * blockDim.x + threadIdx.x;   // (b*C+c)*W + w
    if (tid >= NB * NC * NW) return;
    int w  = tid & (NW - 1);
    int bc = tid >> 8;             // tid / NW
    int c  = bc & (NC - 1);
    long base = (long)bc * (NH * NW) + w;
    const long PLANE = (long)NB * NC * NH * NW;

    if (blockIdx.y == 0) {
        // down: h0 = x[0], then forward
        float wc = w_down[c], bb = b_down[c];
        float* o = out + 2 * PLANE;
        float h = x[base];
        o[base] = h;
        long idx = base;
        #pragma unroll 4
        for (int hh = 1; hh < NH; ++hh) {
            idx += NW;
            h = fmaxf(wc * h + bb + x[idx], 0.0f);
            o[idx] = h;
        }
    } else {
        // up: h0 = x[H-1], then backward
        float wc = w_up[c], bb = b_up[c];
        float* o = out + 0 * PLANE;
        long idx = base + (long)(NH - 1) * NW;
        float h = x[idx];
        o[idx] = h;
        #pragma unroll 4
        for (int hh = NH - 2; hh >= 0; --hh) {
            idx -= NW;
            h = fmaxf(wc * h + bb + x[idx], 0.0f);
            o[idx] = h;
        }
    }
}

// Horizontal scans: blockIdx.y==0 -> right (out slot 1), ==1 -> left (out slot 3).
// Thread per (b,c,h) row; float4 loads/stores along w.
__global__ __launch_bounds__(256) void irnn_horizontal(
    const float* __restrict__ x,
    const float* __restrict__ w_right, const float* __restrict__ b_right,
    const float* __restrict__ w_left,  const float* __restrict__ b_left,
    float* __restrict__ out)
{
    int tid = blockIdx.x * blockDim.x + threadIdx.x;   // (b*C+c)*H + h
    if (tid >= NB * NC * NH) return;
    int c = (tid >> 8) & (NC - 1);   // (tid / NH) % NC
    long base = (long)tid * NW;
    const long PLANE = (long)NB * NC * NH * NW;
    const float4* xr = (const float4*)(x + base);

    if (blockIdx.y == 0) {
        float wc = w_right[c], bb = b_right[c];
        float4* o = (float4*)(out + 1 * PLANE + base);
        float h = 0.0f;
        {   // v = 0: boundary is raw x
            float4 xv = xr[0];
            float4 ov;
            h = xv.x;                              ov.x = h;
            h = fmaxf(wc * h + bb + xv.y, 0.0f);   ov.y = h;
            h = fmaxf(wc * h + bb + xv.z, 0.0f);   ov.z = h;
            h = fmaxf(wc * h + bb + xv.w, 0.0f);   ov.w = h;
            o[0] = ov;
        }
        for (int v = 1; v < NW / 4; ++v) {
            float4 xv = xr[v];
            float4 ov;
            h = fmaxf(wc * h + bb + xv.x, 0.0f);   ov.x = h;
            h = fmaxf(wc * h + bb + xv.y, 0.0f);   ov.y = h;
            h = fmaxf(wc * h + bb + xv.z, 0.0f);   ov.z = h;
            h = fmaxf(wc * h + bb + xv.w, 0.0f);   ov.w = h;
            o[v] = ov;
        }
    } else {
        float wc = w_left[c], bb = b_left[c];
        float4* o = (float4*)(out + 3 * PLANE + base);
        float h = 0.0f;
        {   // v = W/4-1: boundary is raw x at w = W-1
            float4 xv = xr[NW / 4 - 1];
            float4 ov;
            h = xv.w;                              ov.w = h;
            h = fmaxf(wc * h + bb + xv.z, 0.0f);   ov.z = h;
            h = fmaxf(wc * h + bb + xv.y, 0.0f);   ov.y = h;
            h = fmaxf(wc * h + bb + xv.x, 0.0f);   ov.x = h;
            o[NW / 4 - 1] = ov;
        }
        for (int v = NW / 4 - 2; v >= 0; --v) {
            float4 xv = xr[v];
            float4 ov;
            h = fmaxf(wc * h + bb + xv.w, 0.0f);   ov.w = h;
            h = fmaxf(wc * h + bb + xv.z, 0.0f);   ov.z = h;
            h = fmaxf(wc * h + bb + xv.y, 0.0f);   ov.y = h;
            h = fmaxf(wc * h + bb + xv.x, 0.0f);   ov.x = h;
            o[v] = ov;
        }
    }
}

extern "C" void kernel_launch(void* const* d_in, const int* in_sizes, int n_in,
                              void* d_out, int out_size, void* d_ws, size_t ws_size,
                              hipStream_t stream) {
    const float* x       = (const float*)d_in[0];
    const float* w_up    = (const float*)d_in[1];
    const float* w_right = (const float*)d_in[2];
    const float* w_down  = (const float*)d_in[3];
    const float* w_left  = (const float*)d_in[4];
    const float* b_up    = (const float*)d_in[5];
    const float* b_right = (const float*)d_in[6];
    const float* b_down  = (const float*)d_in[7];
    const float* b_left  = (const float*)d_in[8];
    float* out = (float*)d_out;

    // Vertical: B*C*W threads per direction
    {
        int n = NB * NC * NW;
        dim3 grid((n + 255) / 256, 2);
        irnn_vertical<<<grid, 256, 0, stream>>>(x, w_down, b_down, w_up, b_up, out);
    }
    // Horizontal: B*C*H threads per direction
    {
        int n = NB * NC * NH;
        dim3 grid((n + 255) / 256, 2);
        irnn_horizontal<<<grid, 256, 0, stream>>>(x, w_right, b_right, w_left, b_left, out);
    }
}

// Round 2
// 348.664 us; speedup vs baseline: 1.3596x; 1.3596x over previous
//
#include <hip/hip_runtime.h>

#define NB 4
#define NC 64
#define NH 256
#define NW 256
#define PLANE ((long)NB * NC * NH * NW)   // 16.78M elements per direction

// Fused kernel: blockIdx.y = direction (0=up, 1=right, 2=down, 3=left),
// matching the reference's output stacking order.
// Vertical dirs (0,2): thread per (b,c,w) column, coalesced row-wise access,
//   8-deep explicit load batches for latency hiding.
// Horizontal dirs (1,3): block per (b,c) slab, thread per h-row, LDS-transpose
//   tiles of 256 rows x 32 cols (stride 33 -> <=2-way bank conflicts = free).
__global__ __launch_bounds__(256) void irnn_fused(
    const float* __restrict__ x,
    const float* __restrict__ w_up,    const float* __restrict__ b_up,
    const float* __restrict__ w_right, const float* __restrict__ b_right,
    const float* __restrict__ w_down,  const float* __restrict__ b_down,
    const float* __restrict__ w_left,  const float* __restrict__ b_left,
    float* __restrict__ out)
{
    __shared__ float tile[256 * 33];   // 33.8 KB -> 4 blocks/CU, 16 waves/CU

    const int dir = blockIdx.y;
    const int t   = threadIdx.x;

    if (dir == 0 || dir == 2) {
        // ---------------- vertical scans ----------------
        int tid = blockIdx.x * 256 + t;        // (b*C + c)*W + w
        int w   = tid & (NW - 1);
        int bc  = tid >> 8;
        int c   = bc & (NC - 1);
        long base = (long)bc * (NH * NW) + w;
        float* o = out + (long)dir * PLANE;

        if (dir == 2) {
            // down: forward scan over h
            float wc = w_down[c], bb = b_down[c];
            float h = x[base];
            o[base] = h;
            long idx = base;
            // rows 1..248 in 31 batches of 8, then 7-row tail
            for (int batch = 0; batch < 31; ++batch) {
                float v[8];
                #pragma unroll
                for (int k = 0; k < 8; ++k) v[k] = x[idx + (long)(k + 1) * NW];
                #pragma unroll
                for (int k = 0; k < 8; ++k) {
                    h = fmaxf(wc * h + bb + v[k], 0.0f);
                    o[idx + (long)(k + 1) * NW] = h;
                }
                idx += 8L * NW;
            }
            float v[7];
            #pragma unroll
            for (int k = 0; k < 7; ++k) v[k] = x[idx + (long)(k + 1) * NW];
            #pragma unroll
            for (int k = 0; k < 7; ++k) {
                h = fmaxf(wc * h + bb + v[k], 0.0f);
                o[idx + (long)(k + 1) * NW] = h;
            }
        } else {
            // up: backward scan over h
            float wc = w_up[c], bb = b_up[c];
            long idx = base + (long)(NH - 1) * NW;
            float h = x[idx];
            o[idx] = h;
            for (int batch = 0; batch < 31; ++batch) {
                float v[8];
                #pragma unroll
                for (int k = 0; k < 8; ++k) v[k] = x[idx - (long)(k + 1) * NW];
                #pragma unroll
                for (int k = 0; k < 8; ++k) {
                    h = fmaxf(wc * h + bb + v[k], 0.0f);
                    o[idx - (long)(k + 1) * NW] = h;
                }
                idx -= 8L * NW;
            }
            float v[7];
            #pragma unroll
            for (int k = 0; k < 7; ++k) v[k] = x[idx - (long)(k + 1) * NW];
            #pragma unroll
            for (int k = 0; k < 7; ++k) {
                h = fmaxf(wc * h + bb + v[k], 0.0f);
                o[idx - (long)(k + 1) * NW] = h;
            }
        }
    } else {
        // ---------------- horizontal scans ----------------
        const int bc = blockIdx.x;             // b*C + c slab
        const int c  = bc & (NC - 1);
        const bool fwd = (dir == 1);
        const float wc = fwd ? w_right[c] : w_left[c];
        const float bb = fwd ? b_right[c] : b_left[c];
        float* o = out + (long)dir * PLANE;
        const long slab = (long)bc * (NH * NW);

        const int r  = t >> 3;                 // 0..31  (row group for ld/st)
        const int c4 = t & 7;                  // 0..7   (float4 col within chunk)

        float h = 0.0f;
        for (int ci = 0; ci < 8; ++ci) {
            const int w0 = fwd ? ci * 32 : 224 - ci * 32;

            // load 256x32 chunk, coalesced float4 (8 x 128B segments / wave)
            #pragma unroll
            for (int k = 0; k < 8; ++k) {
                int row = r + 32 * k;
                float4 v = *(const float4*)(x + slab + (long)row * NW + w0 + c4 * 4);
                float* dst = &tile[row * 33 + c4 * 4];
                dst[0] = v.x; dst[1] = v.y; dst[2] = v.z; dst[3] = v.w;
            }
            __syncthreads();

            // scan my row (thread t owns h-row t); stride-33 -> 2-way = free
            float* myrow = &tile[t * 33];
            if (fwd) {
                int v0 = 0;
                if (ci == 0) { h = myrow[0]; v0 = 1; }
                for (int v = v0; v < 32; ++v) {
                    float xv = myrow[v];
                    h = fmaxf(wc * h + bb + xv, 0.0f);
                    myrow[v] = h;
                }
            } else {
                int v0 = 31;
                if (ci == 0) { h = myrow[31]; v0 = 30; }
                for (int v = v0; v >= 0; --v) {
                    float xv = myrow[v];
                    h = fmaxf(wc * h + bb + xv, 0.0f);
                    myrow[v] = h;
                }
            }
            __syncthreads();

            // store chunk back, coalesced float4
            #pragma unroll
            for (int k = 0; k < 8; ++k) {
                int row = r + 32 * k;
                const float* src = &tile[row * 33 + c4 * 4];
                float4 v;
                v.x = src[0]; v.y = src[1]; v.z = src[2]; v.w = src[3];
                *(float4*)(o + slab + (long)row * NW + w0 + c4 * 4) = v;
            }
            __syncthreads();
        }
    }
}

extern "C" void kernel_launch(void* const* d_in, const int* in_sizes, int n_in,
                              void* d_out, int out_size, void* d_ws, size_t ws_size,
                              hipStream_t stream) {
    const float* x       = (const float*)d_in[0];
    const float* w_up    = (const float*)d_in[1];
    const float* w_right = (const float*)d_in[2];
    const float* w_down  = (const float*)d_in[3];
    const float* w_left  = (const float*)d_in[4];
    const float* b_up    = (const float*)d_in[5];
    const float* b_right = (const float*)d_in[6];
    const float* b_down  = (const float*)d_in[7];
    const float* b_left  = (const float*)d_in[8];
    float* out = (float*)d_out;

    dim3 grid(256, 4);   // x: 256 blocks per direction, y: direction
    irnn_fused<<<grid, 256, 0, stream>>>(
        x, w_up, b_up, w_right, b_right, w_down, b_down, w_left, b_left, out);
}